// Round 17
// baseline (117.244 us; speedup 1.0000x reference)
//
#include <hip/hip_runtime.h>

typedef unsigned short u16;
typedef unsigned int u32;
typedef __attribute__((ext_vector_type(8))) short sh8;           // 8 bf16 (4 VGPR)
typedef __attribute__((ext_vector_type(8))) unsigned short us8;
typedef __attribute__((ext_vector_type(2))) unsigned int ui2;
typedef __attribute__((ext_vector_type(4))) float f4;

__device__ __forceinline__ float bf2f(u16 u) {
  union { unsigned u; float f; } v; v.u = ((unsigned)u) << 16; return v.f;
}
__device__ __forceinline__ u16 f2bf(float f) {
  union { float f; unsigned u; } v; v.f = f;
  unsigned r = v.u + 0x7fffu + ((v.u >> 16) & 1u);   // RNE, inputs finite
  return (u16)(r >> 16);
}
// pack 4 f32 -> 4 bf16 (RNE) in 2 insts
__device__ __forceinline__ ui2 pk4(float a, float b, float c, float d) {
  u32 lo, hi;
  asm("v_cvt_pk_bf16_f32 %0, %1, %2" : "=v"(lo) : "v"(a), "v"(b));
  asm("v_cvt_pk_bf16_f32 %0, %1, %2" : "=v"(hi) : "v"(c), "v"(d));
  ui2 r; r[0] = lo; r[1] = hi; return r;
}
// async global->LDS, 16B per lane; dest = wave-uniform base + lane*16
__device__ __forceinline__ void gl16(const void* g, void* l) {
  __builtin_amdgcn_global_load_lds(
      (const __attribute__((address_space(1))) unsigned int*)g,
      (__attribute__((address_space(3))) unsigned int*)l, 16, 0, 0);
}

// ---- fused: f32->bf16 cvt (bx<2048) | weight transpose (2048..3583) | x-pool (>=3584) ----
// Wt rows: [0,1024)=Wq | [1024,3072)=Wl | [3072,5120)=Wc | [5120,6144)=Wo
__global__ __launch_bounds__(256)
void k_prep(const float* __restrict__ x, const float* __restrict__ Wq,
            const float* __restrict__ Wl, const float* __restrict__ Wc,
            const float* __restrict__ Wo, u16* __restrict__ xb,
            u16* __restrict__ Wt, u16* __restrict__ xp) {
  __shared__ u16 tile[64][65];
  const int bx = blockIdx.x;
  const int t = threadIdx.x;
  if (bx < 2048) {
    const int idx = bx * 256 + t;            // < 524288 = 4194304/8
    const f4* p = (const f4*)x + (size_t)idx * 2;
    f4 a = p[0], b = p[1];
    us8 o;
    o[0] = f2bf(a[0]); o[1] = f2bf(a[1]); o[2] = f2bf(a[2]); o[3] = f2bf(a[3]);
    o[4] = f2bf(b[0]); o[5] = f2bf(b[1]); o[6] = f2bf(b[2]); o[7] = f2bf(b[3]);
    ((us8*)xb)[idx] = o;
    return;
  }
  if (bx >= 3584) {                          // x-pool: xp[b*128+j] = mean32 x rows (f32 src)
    const int row = bx - 3584;               // 0..255
    const int b = row >> 7, j = row & 127;
    const int c0 = t * 4;
    if (j == 127) { *(ui2*)&xp[(size_t)row * 1024 + c0] = ui2{0u, 0u}; return; }
    const float* src = x + ((size_t)(b * 2048 + j * 16)) * 1024 + c0;
    float s0 = 0.f, s1 = 0.f, s2 = 0.f, s3 = 0.f;
    #pragma unroll 8
    for (int r = 0; r < 32; r++) {
      f4 v = *(const f4*)(src + (size_t)r * 1024);
      s0 += v[0]; s1 += v[1]; s2 += v[2]; s3 += v[3];
    }
    const float inv = 1.f / 32.f;
    *(ui2*)&xp[(size_t)row * 1024 + c0] = pk4(s0 * inv, s1 * inv, s2 * inv, s3 * inv);
    return;
  }
  const int id = bx - 2048;                  // 0..1535
  const int n0 = (id % 96) * 64;
  const int k0 = (id / 96) * 64;
  const float* src; int ld, col0;
  if (n0 < 1024)      { src = Wq; ld = 1024; col0 = n0; }
  else if (n0 < 3072) { src = Wl; ld = 2048; col0 = n0 - 1024; }
  else if (n0 < 5120) { src = Wc; ld = 2048; col0 = n0 - 3072; }
  else                { src = Wo; ld = 1024; col0 = n0 - 5120; }
  const int r = t >> 2;          // 0..63
  const int c0 = (t & 3) * 16;   // 0,16,32,48
  const f4* sp = (const f4*)(src + (size_t)(k0 + r) * ld + col0 + c0);
  const f4 va = sp[0], vb = sp[1], vc = sp[2], vd = sp[3];
  #pragma unroll
  for (int j = 0; j < 4; j++) {
    tile[r][c0 + j]      = f2bf(va[j]);
    tile[r][c0 + 4 + j]  = f2bf(vb[j]);
    tile[r][c0 + 8 + j]  = f2bf(vc[j]);
    tile[r][c0 + 12 + j] = f2bf(vd[j]);
  }
  __syncthreads();
  us8 o0, o1;
  #pragma unroll
  for (int j = 0; j < 8; j++) { o0[j] = tile[c0 + j][r]; o1[j] = tile[c0 + 8 + j][r]; }
  u16* op = Wt + (size_t)(n0 + r) * 1024 + k0 + c0;
  *(us8*)op       = o0;
  *(us8*)(op + 8) = o1;
}

// ======= gemm1: BK=32 3-slot counted-vmcnt pipeline (r10/r14-verified), 128x128 =======
// grid dim3(24,32) = 768 blocks = 3 blocks/CU x 256 CU exactly -> zero tail.
// LDS: 3 slots x (A[128][32] + B[128][32]) = 48 KB. Iter kt: STAGE(kt+2) ->
// 16 MFMA on tile kt -> vmcnt(4) (retires kt+1, issued two iters earlier) ->
// s_barrier. Bank spread cs=(g+(row>>1))&3, source pre-permuted (0 conflicts).
__global__ __launch_bounds__(256)
void k_gemm32(const u16* __restrict__ A, const u16* __restrict__ Bt,
              u16* __restrict__ C, int M, int N, int K) {
  constexpr int TSZ = 8192;                  // u16 per slot: A 4096 | B 4096
  __shared__ __align__(16) u16 LB[3 * TSZ];  // 49,152 B
  const int bm0 = blockIdx.y * 128;
  const int bn0 = blockIdx.x * 128;
  const int tid = threadIdx.x;
  const int wave = tid >> 6;
  const int lane = tid & 63;
  const int fr = lane & 15;
  const int g  = lane >> 4;
  const int wr = wave >> 1, wc = wave & 1;
  const int KT = K >> 5;
  f4 acc[4][4] = {};

  auto STAGE = [&](int t) {
    const int s = t - (t / 3) * 3;
    const size_t kofs = (size_t)t << 5;
    #pragma unroll
    for (int j = 0; j < 2; j++) {
      const int kbase = (wave * 2 + j) * 64;   // wave-uniform chunk base
      const int gidx = kbase + lane;           // 0..511
      const int row = gidx >> 2;
      const int cs = gidx & 3;                 // dest slot within row
      const int cg = (cs - (row >> 1)) & 3;    // global chunk it must hold
      gl16(A  + (size_t)(bm0 + row) * K + kofs + cg * 8, &LB[s * TSZ + kbase * 8]);
      gl16(Bt + (size_t)(bn0 + row) * K + kofs + cg * 8, &LB[s * TSZ + 4096 + kbase * 8]);
    }
  };

  STAGE(0); STAGE(1);
  __builtin_amdgcn_sched_barrier(0);
  asm volatile("s_waitcnt vmcnt(4)" ::: "memory");   // tile 0 resident
  __builtin_amdgcn_s_barrier();
  __builtin_amdgcn_sched_barrier(0);

  for (int kt = 0; kt < KT; kt++) {
    const int s = kt - (kt / 3) * 3;
    const bool pf = (kt + 2) < KT;
    if (pf) STAGE(kt + 2);
    __builtin_amdgcn_sched_barrier(0);            // issue stage before compute
    const u16* As = &LB[s * TSZ];
    const u16* Bs = &LB[s * TSZ + 4096];
    sh8 af[4], bfv[4];
    #pragma unroll
    for (int mi = 0; mi < 4; mi++) {
      const int row = wr * 64 + mi * 16 + fr;
      const int cs = (g + (row >> 1)) & 3;
      af[mi] = *(const sh8*)&As[row * 32 + cs * 8];
    }
    #pragma unroll
    for (int ni = 0; ni < 4; ni++) {
      const int row = wc * 64 + ni * 16 + fr;
      const int cs = (g + (row >> 1)) & 3;
      bfv[ni] = *(const sh8*)&Bs[row * 32 + cs * 8];
    }
    #pragma unroll
    for (int mi = 0; mi < 4; mi++)
      #pragma unroll
      for (int ni = 0; ni < 4; ni++)
        acc[mi][ni] = __builtin_amdgcn_mfma_f32_16x16x32_bf16(af[mi], bfv[ni], acc[mi][ni], 0, 0, 0);
    __builtin_amdgcn_sched_barrier(0);
    if (pf) asm volatile("s_waitcnt vmcnt(4)" ::: "memory");   // retire kt+1
    else    asm volatile("s_waitcnt vmcnt(0)" ::: "memory");   // tail drain
    __builtin_amdgcn_s_barrier();
    __builtin_amdgcn_sched_barrier(0);
  }

  const int rb = bm0 + wr * 64 + g * 4;
  const int cb = bn0 + wc * 64 + fr;
  #pragma unroll
  for (int mi = 0; mi < 4; mi++)
    #pragma unroll
    for (int ni = 0; ni < 4; ni++)
      #pragma unroll
      for (int r = 0; r < 4; r++)
        C[(size_t)(rb + mi * 16 + r) * N + cb + ni * 16] = f2bf(acc[mi][ni][r]);
}

// ======= 64x64 dbuf gl_lds GEMM (r15-verified structure), templated output =======
// OUT_BF16=true: pooled proj -> C2 bf16 (grid dim3(32,4)).
// OUT_BF16=false: final y@Wo -> out f32 (grid dim3(16,64)).
template<bool OUT_BF16>
__global__ __launch_bounds__(256)
void k_gemm2(const u16* __restrict__ A, const u16* __restrict__ Bt,
             void* __restrict__ Cout, int M, int N, int K) {
  __shared__ __align__(16) u16 LB[2][2][4096];   // [buf][A/B][64*64]
  const int bm0 = blockIdx.y * 64;
  const int bn0 = blockIdx.x * 64;
  const int tid = threadIdx.x;
  const int wave = tid >> 6;
  const int lane = tid & 63;
  const int fr = lane & 15;
  const int g  = lane >> 4;
  const int wr = wave >> 1, wc = wave & 1;
  const int srow = lane >> 3;
  const int schunk = (lane & 7) ^ (srow & 7);
  const u16* Asrc = A  + (size_t)(bm0 + wave * 16 + srow) * K + schunk * 8;
  const u16* Bsrc = Bt + (size_t)(bn0 + wave * 16 + srow) * K + schunk * 8;
  f4 acc[2][2] = {};
  const int KT = K >> 6;

  #pragma unroll
  for (int i = 0; i < 2; i++) {
    gl16(Asrc + (size_t)(i * 8) * K, &LB[0][0][(wave * 16 + i * 8) * 64]);
    gl16(Bsrc + (size_t)(i * 8) * K, &LB[0][1][(wave * 16 + i * 8) * 64]);
  }
  __syncthreads();

  int cur = 0;
  for (int kt = 0; kt < KT; kt++) {
    if (kt + 1 < KT) {
      const size_t go = (size_t)(kt + 1) * 64;
      #pragma unroll
      for (int i = 0; i < 2; i++) {
        gl16(Asrc + (size_t)(i * 8) * K + go, &LB[cur ^ 1][0][(wave * 16 + i * 8) * 64]);
        gl16(Bsrc + (size_t)(i * 8) * K + go, &LB[cur ^ 1][1][(wave * 16 + i * 8) * 64]);
      }
    }
    __builtin_amdgcn_sched_barrier(0);   // keep prefetch issue ahead of compute
    const u16* As = &LB[cur][0][0];
    const u16* Bs = &LB[cur][1][0];
    #pragma unroll
    for (int kh = 0; kh < 2; kh++) {
      sh8 af[2], bfv[2];
      const int ch = ((kh * 4 + g) ^ (fr & 7)) * 8;
      #pragma unroll
      for (int mi = 0; mi < 2; mi++)
        af[mi] = *(const sh8*)&As[(wr * 32 + mi * 16 + fr) * 64 + ch];
      #pragma unroll
      for (int ni = 0; ni < 2; ni++)
        bfv[ni] = *(const sh8*)&Bs[(wc * 32 + ni * 16 + fr) * 64 + ch];
      #pragma unroll
      for (int mi = 0; mi < 2; mi++)
        #pragma unroll
        for (int ni = 0; ni < 2; ni++)
          acc[mi][ni] = __builtin_amdgcn_mfma_f32_16x16x32_bf16(af[mi], bfv[ni], acc[mi][ni], 0, 0, 0);
    }
    __syncthreads();   // drains vmcnt (prefetch landed) + lgkmcnt
    cur ^= 1;
  }

  const int rbase = bm0 + wr * 32 + g * 4;
  const int cbase = bn0 + wc * 32 + fr;
  #pragma unroll
  for (int mi = 0; mi < 2; mi++)
    #pragma unroll
    for (int ni = 0; ni < 2; ni++)
      #pragma unroll
      for (int r = 0; r < 4; r++) {
        const size_t off = (size_t)(rbase + mi * 16 + r) * N + (cbase + ni * 16);
        if constexpr (OUT_BF16) ((u16*)Cout)[off] = f2bf(acc[mi][ni][r]);
        else                    ((float*)Cout)[off] = acc[mi][ni][r];
      }
}

// ------- fused: C2 reorg -> kpb,vpT (bx<4) | vl transpose (bx in [4,36)) -------
// C2[256 rows=b*128+j][2048 cols = kc_pool(0..1023) | vc_pool(1024..2047)]
__global__ __launch_bounds__(256)
void k_poolvt(const u16* __restrict__ proj, const u16* __restrict__ C2,
              u16* __restrict__ kpb, u16* __restrict__ vpT, u16* __restrict__ vlT) {
  __shared__ u16 tile[64][72];
  const int bx = blockIdx.x;
  const int bh = blockIdx.y;
  const int b = bh >> 4, h = bh & 15;
  const int t = threadIdx.x;
  if (bx < 4) {
    const int d = t & 63;
    const int jj = t >> 6;             // 0..3
    #pragma unroll
    for (int j0 = 0; j0 < 8; j0++) {
      const int j = bx * 32 + jj * 8 + j0;    // 0..127 (row 127 = zeros from xp pad)
      const size_t crow = (size_t)(b * 128 + j) * 2048;
      kpb[((size_t)bh * 128 + j) * 64 + d] = C2[crow + h * 64 + d];
      vpT[((size_t)bh * 64 + d) * 128 + j] = C2[crow + 1024 + h * 64 + d];
    }
    return;
  }
  const int tt = bx - 4;               // 0..31 token tile
  const int r = t >> 2;                // 0..63
  const int c0 = (t & 3) * 16;
  const u16* sp = proj + (size_t)(b * 2048 + tt * 64 + r) * 3072 + 2048 + h * 64 + c0;
  us8 v0 = *(const us8*)sp;
  us8 v1 = *(const us8*)(sp + 8);
  #pragma unroll
  for (int jj = 0; jj < 8; jj++) { tile[r][c0 + jj] = v0[jj]; tile[r][c0 + 8 + jj] = v1[jj]; }
  __syncthreads();
  u16* op = vlT + ((size_t)bh * 64 + r) * 2048 + tt * 64 + c0;
  #pragma unroll
  for (int jj = 0; jj < 16; jj++) op[jj] = tile[c0 + jj][r];
}

// -------- fused attention: bx<32 local -> yb, bx>=32 comp -> yb2 (concurrent) --------
// proj layout [4096][3072]: q(0) | kl(1024) | vl(2048)
__global__ __launch_bounds__(256)
void k_attn(const u16* __restrict__ proj, const u16* __restrict__ vlT,
            const u16* __restrict__ kpb, const u16* __restrict__ vpT,
            u16* __restrict__ yb, u16* __restrict__ yb2) {
  __shared__ __align__(16) u16 SB[26688];   // 53376 B -> 3 blocks/CU
  const int bx = blockIdx.x;
  const int bh = blockIdx.y;
  const int b = bh >> 4, h = bh & 15;
  const int tid = threadIdx.x;
  const int wave = tid >> 6;
  const int lane = tid & 63;
  const int fr = lane & 15;
  const int g  = lane >> 4;
  const int ko = g * 8;
  const u16* prow = proj + (size_t)(b * 2048) * 3072;

  if (bx < 32) {
    // ================= LOCAL =================
    const int qt = bx;
    const int q0 = qt * 64;
    const int wq0 = q0 + wave * 16;
    const int i_abs = wq0 + fr;
    const u16* klb = prow + 1024 + h * 64;
    const u16* vltb = vlT + (size_t)bh * 64 * 2048;

    #pragma unroll
    for (int it = 0; it < 7; it++) {
      const int inst = it * 4 + wave;
      if (inst < 27) {
        const int c = inst * 64 + lane;
        const int row = c / 9;
        const int sl = c - row * 9;
        int jg = q0 - 128 + row; if (jg < 0) jg = 0;
        gl16(klb + (size_t)jg * 3072 + (sl & 7) * 8, &SB[inst * 512]);
      }
    }
    #pragma unroll
    for (int it = 0; it < 7; it++) {
      const int inst = it * 4 + wave;
      if (inst < 25) {
        const int c = inst * 64 + lane;
        const int row = c / 25;
        const int sl = c - row * 25;
        int tc = q0 - 128 + (sl < 24 ? sl : 0) * 8; if (tc < 0) tc = 0;
        gl16(vltb + (size_t)row * 2048 + tc, &SB[13824 + inst * 512]);
      }
    }
    const sh8 bq0 = *(const sh8*)(prow + (size_t)i_abs * 3072 + h * 64 + ko);
    const sh8 bq1 = *(const sh8*)(prow + (size_t)i_abs * 3072 + h * 64 + 32 + ko);
    __syncthreads();   // barrier 1

    f4 st[9];
    #pragma unroll
    for (int f = 0; f < 9; f++) st[f] = f4{0.f, 0.f, 0.f, 0.f};
    #pragma unroll
    for (int kh = 0; kh < 2; kh++) {
      const sh8 bq = kh ? bq1 : bq0;
      #pragma unroll
      for (int f = 0; f < 9; f++) {
        sh8 ak = *(const sh8*)&SB[(wave * 16 + f * 16 + fr) * 72 + kh * 32 + ko];
        st[f] = __builtin_amdgcn_mfma_f32_16x16x32_bf16(ak, bq, st[f], 0, 0, 0);
      }
    }
    const int klo = 128 - wq0;
    float m = -1e30f;
    #pragma unroll
    for (int f = 0; f < 9; f++)
      #pragma unroll
      for (int r = 0; r < 4; r++) {
        const int kk = f * 16 + g * 4 + r;
        const bool ok = (kk > fr) && (kk <= fr + 128) && (kk >= klo);
        const float v = ok ? st[f][r] * 0.125f : -1e30f;
        st[f][r] = v; m = fmaxf(m, v);
      }
    m = fmaxf(m, __shfl_xor(m, 16));
    m = fmaxf(m, __shfl_xor(m, 32));
    float l = 0.f;
    #pragma unroll
    for (int f = 0; f < 9; f++)
      #pragma unroll
      for (int r = 0; r < 4; r++) {
        const float p = __expf(st[f][r] - m);
        st[f][r] = p; l += p;
      }
    l += __shfl_xor(l, 16);
    l += __shfl_xor(l, 32);
    const float inv = 1.f / l;

    __syncthreads();   // barrier 2: KL region becomes P

    u16* Pw = &SB[wave * 2688];     // [16][168]
    #pragma unroll
    for (int f = 0; f < 9; f++)
      *(ui2*)&Pw[fr * 168 + f * 16 + g * 4] =
          pk4(st[f][0] * inv, st[f][1] * inv, st[f][2] * inv, st[f][3] * inv);
    *(ui2*)&Pw[fr * 168 + 144 + g * 4] = ui2{0u, 0u};

    f4 yacc[4];
    #pragma unroll
    for (int ni = 0; ni < 4; ni++) yacc[ni] = f4{0.f, 0.f, 0.f, 0.f};
    #pragma unroll
    for (int ks = 0; ks < 5; ks++) {
      sh8 pa = *(const sh8*)&Pw[fr * 168 + ks * 32 + ko];
      const int col = wave * 16 + ks * 32 + ko;
      #pragma unroll
      for (int ni = 0; ni < 4; ni++) {
        sh8 vb = *(const sh8*)&SB[13824 + (ni * 16 + fr) * 200 + col];
        yacc[ni] = __builtin_amdgcn_mfma_f32_16x16x32_bf16(pa, vb, yacc[ni], 0, 0, 0);
      }
    }

    #pragma unroll
    for (int ni = 0; ni < 4; ni++)
      #pragma unroll
      for (int r = 0; r < 4; r++)
        Pw[(4 * g + r) * 72 + ni * 16 + fr] = f2bf(yacc[ni][r]);
    const int row = lane >> 2;
    const int c0 = (lane & 3) * 16;
    u16* gy = yb + (size_t)(b * 2048 + wq0 + row) * 1024 + h * 64 + c0;
    *(us8*)gy       = *(const us8*)&Pw[row * 72 + c0];
    *(us8*)(gy + 8) = *(const us8*)&Pw[row * 72 + c0 + 8];
    return;
  }

  // ================= COMPRESSED =================
  const int qt = bx - 32;
  const int wq0 = qt * 64 + wave * 16;
  const int i_abs = wq0 + fr;
  const u16* kpr = kpb + (size_t)bh * 8192;
  const u16* vptb = vpT + (size_t)bh * 8192;

  #pragma unroll
  for (int it = 0; it < 5; it++) {
    const int inst = it * 4 + wave;
    if (inst < 18) {
      const int c = inst * 64 + lane;
      const int row = c / 9;
      const int sl = c - row * 9;
      gl16(kpr + (size_t)row * 64 + (sl & 7) * 8, &SB[inst * 512]);
    }
  }
  #pragma unroll
  for (int it = 0; it < 5; it++) {
    const int inst = it * 4 + wave;
    if (inst < 17) {
      const int c = inst * 64 + lane;
      const int row = c / 17;
      const int sl = c - row * 17;
      gl16(vptb + (size_t)row * 128 + (sl & 15) * 8, &SB[9216 + inst * 512]);
    }
  }
  const sh8 bq0 = *(const sh8*)(prow + (size_t)i_abs * 3072 + h * 64 + ko);
  const sh8 bq1 = *(const sh8*)(prow + (size_t)i_abs * 3072 + h * 64 + 32 + ko);
  const int yrow = lane >> 2;
  const int yc0 = (lane & 3) * 16;
  __syncthreads();   // barrier 1

  const int nf = ((wq0 + 15) >> 8) + 1;   // 1..8, wave-uniform
  f4 sc[8];
  #pragma unroll
  for (int f = 0; f < 8; f++) sc[f] = f4{0.f, 0.f, 0.f, 0.f};
  #pragma unroll
  for (int kh = 0; kh < 2; kh++) {
    const sh8 bq = kh ? bq1 : bq0;
    #pragma unroll
    for (int f = 0; f < 8; f++)
      if (f < nf) {
        sh8 ak = *(const sh8*)&SB[(f * 16 + fr) * 72 + kh * 32 + ko];
        sc[f] = __builtin_amdgcn_mfma_f32_16x16x32_bf16(ak, bq, sc[f], 0, 0, 0);
      }
  }
  float m2 = -1e30f;
  #pragma unroll
  for (int f = 0; f < 8; f++)
    #pragma unroll
    for (int r = 0; r < 4; r++) {
      const int jj = f * 16 + g * 4 + r;
      const bool ok = (jj <= 126) && (16 * jj <= i_abs);
      const float v = ok ? sc[f][r] * 0.125f : -1e30f;
      sc[f][r] = v; m2 = fmaxf(m2, v);
    }
  m2 = fmaxf(m2, __shfl_xor(m2, 16));
  m2 = fmaxf(m2, __shfl_xor(m2, 32));
  float l2 = 0.f;
  #pragma unroll
  for (int f = 0; f < 8; f++)
    #pragma unroll
    for (int r = 0; r < 4; r++) {
      const float p = __expf(sc[f][r] - m2);
      sc[f][r] = p; l2 += p;
    }
  l2 += __shfl_xor(l2, 16);
  l2 += __shfl_xor(l2, 32);
  const float inv2 = 1.f / l2;

  __syncthreads();   // barrier 2: KC region becomes P

  u16* Pw = &SB[wave * 2176];     // [16][136]
  #pragma unroll
  for (int f = 0; f < 8; f++)
    if (f < nf)
      *(ui2*)&Pw[fr * 136 + f * 16 + g * 4] =
          pk4(sc[f][0] * inv2, sc[f][1] * inv2, sc[f][2] * inv2, sc[f][3] * inv2);
  if (nf & 1)
    *(ui2*)&Pw[fr * 136 + nf * 16 + g * 4] = ui2{0u, 0u};

  f4 yacc[4];
  #pragma unroll
  for (int ni = 0; ni < 4; ni++) yacc[ni] = f4{0.f, 0.f, 0.f, 0.f};
  const int nks = (nf + 1) >> 1;
  #pragma unroll
  for (int ks = 0; ks < 4; ks++)
    if (ks < nks) {
      sh8 pa = *(const sh8*)&Pw[fr * 136 + ks * 32 + ko];
      #pragma unroll
      for (int ni = 0; ni < 4; ni++) {
        sh8 vb = *(const sh8*)&SB[9216 + (ni * 16 + fr) * 136 + ks * 32 + ko];
        yacc[ni] = __builtin_amdgcn_mfma_f32_16x16x32_bf16(pa, vb, yacc[ni], 0, 0, 0);
      }
    }

  #pragma unroll
  for (int ni = 0; ni < 4; ni++)
    #pragma unroll
    for (int r = 0; r < 4; r++)
      Pw[(4 * g + r) * 72 + ni * 16 + fr] = f2bf(yacc[ni][r]);
  u16* gy = yb2 + (size_t)(b * 2048 + wq0 + yrow) * 1024 + h * 64 + yc0;
  *(us8*)gy       = *(const us8*)&Pw[yrow * 72 + yc0];
  *(us8*)(gy + 8) = *(const us8*)&Pw[yrow * 72 + yc0 + 8];
}

// ---- yb += yb2 (bf16, elementwise, 8/thread) ----
__global__ __launch_bounds__(256)
void k_sum(u16* __restrict__ yb, const u16* __restrict__ yb2) {
  const int idx = blockIdx.x * 256 + threadIdx.x;   // < 524288
  us8 a = ((const us8*)yb)[idx];
  us8 b = ((const us8*)yb2)[idx];
  ui2 lo = pk4(bf2f(a[0]) + bf2f(b[0]), bf2f(a[1]) + bf2f(b[1]),
               bf2f(a[2]) + bf2f(b[2]), bf2f(a[3]) + bf2f(b[3]));
  ui2 hi = pk4(bf2f(a[4]) + bf2f(b[4]), bf2f(a[5]) + bf2f(b[5]),
               bf2f(a[6]) + bf2f(b[6]), bf2f(a[7]) + bf2f(b[7]));
  us8 o;
  o[0] = (u16)lo[0]; o[1] = (u16)(lo[0] >> 16); o[2] = (u16)lo[1]; o[3] = (u16)(lo[1] >> 16);
  o[4] = (u16)hi[0]; o[5] = (u16)(hi[0] >> 16); o[6] = (u16)hi[1]; o[7] = (u16)(hi[1] >> 16);
  ((us8*)yb)[idx] = o;
}

extern "C" void kernel_launch(void* const* d_in, const int* in_sizes, int n_in,
                              void* d_out, int out_size, void* d_ws, size_t ws_size,
                              hipStream_t stream) {
  const float* x  = (const float*)d_in[0];
  const float* Wq = (const float*)d_in[1];
  const float* Wl = (const float*)d_in[2];
  const float* Wc = (const float*)d_in[3];
  const float* Wo = (const float*)d_in[4];
  // dkc/dvc unused: n_def == 0 at T=2048.
  float* out = (float*)d_out;
  char* ws = (char*)d_ws;
  // workspace (~65.5 MB): vlT aliases xb (xb dead after gemm32)
  u16* xb   = (u16*)(ws);                       //  8 MB  x bf16 [4096][1024]
  u16* vlT  = (u16*)(ws);                       //  8 MB  vl^T bf16 [32][64][2048] (after gemm32)
  u16* Wt   = (u16*)(ws + 8388608);             // 12 MB  weights^T bf16 [6144][1024]
  u16* proj = (u16*)(ws + 20971520);            // 24 MB  [4096][3072] q|kl|vl bf16
  u16* xp   = (u16*)(ws + 46137344);            // 512 KB pooled x bf16 [256][1024]
  u16* C2   = (u16*)(ws + 46661632);            //  1 MB  pooled proj bf16 [256][2048]
  u16* kpb  = (u16*)(ws + 47710208);            // 512 KB pooled K bf16 [32][128][64]
  u16* vpT  = (u16*)(ws + 48234496);            // 512 KB pooled V^T bf16 [32][64][128]
  u16* yb   = (u16*)(ws + 48758784);            //  8 MB  y_local bf16 [4096][1024]
  u16* yb2  = (u16*)(ws + 57147392);            //  8 MB  y_comp  bf16 [4096][1024]

  k_prep<<<3840, 256, 0, stream>>>(x, Wq, Wl, Wc, Wo, xb, Wt, xp);
  k_gemm32<<<dim3(24, 32), 256, 0, stream>>>(xb, Wt, proj, 4096, 3072, 1024);
  k_gemm2<true><<<dim3(32, 4), 256, 0, stream>>>(xp, Wt + (size_t)3072 * 1024, C2, 256, 2048, 1024);
  k_poolvt<<<dim3(36, 32), 256, 0, stream>>>(proj, C2, kpb, vpT, vlT);
  k_attn<<<dim3(64, 32), 256, 0, stream>>>(proj, vlT, kpb, vpT, yb, yb2);
  k_sum<<<2048, 256, 0, stream>>>(yb, yb2);
  k_gemm2<false><<<dim3(16, 64), 256, 0, stream>>>(yb, Wt + (size_t)5120 * 1024, out, 4096, 1024, 1024);
}

// Round 18
// 116.519 us; speedup vs baseline: 1.0062x; 1.0062x over previous
//
#include <hip/hip_runtime.h>

typedef unsigned short u16;
typedef unsigned int u32;
typedef __attribute__((ext_vector_type(8))) short sh8;           // 8 bf16 (4 VGPR)
typedef __attribute__((ext_vector_type(8))) unsigned short us8;
typedef __attribute__((ext_vector_type(2))) unsigned int ui2;
typedef __attribute__((ext_vector_type(4))) float f4;

__device__ __forceinline__ float bf2f(u16 u) {
  union { unsigned u; float f; } v; v.u = ((unsigned)u) << 16; return v.f;
}
__device__ __forceinline__ u16 f2bf(float f) {
  union { float f; unsigned u; } v; v.f = f;
  unsigned r = v.u + 0x7fffu + ((v.u >> 16) & 1u);   // RNE, inputs finite
  return (u16)(r >> 16);
}
// pack 4 f32 -> 4 bf16 (RNE) in 2 insts
__device__ __forceinline__ ui2 pk4(float a, float b, float c, float d) {
  u32 lo, hi;
  asm("v_cvt_pk_bf16_f32 %0, %1, %2" : "=v"(lo) : "v"(a), "v"(b));
  asm("v_cvt_pk_bf16_f32 %0, %1, %2" : "=v"(hi) : "v"(c), "v"(d));
  ui2 r; r[0] = lo; r[1] = hi; return r;
}
// async global->LDS, 16B per lane; dest = wave-uniform base + lane*16
__device__ __forceinline__ void gl16(const void* g, void* l) {
  __builtin_amdgcn_global_load_lds(
      (const __attribute__((address_space(1))) unsigned int*)g,
      (__attribute__((address_space(3))) unsigned int*)l, 16, 0, 0);
}

// ---- fused: f32->bf16 cvt (bx<2048) | weight transpose (2048..3583) | x-pool (>=3584) ----
// Wt rows: [0,1024)=Wq | [1024,3072)=Wl | [3072,5120)=Wc | [5120,6144)=Wo
__global__ __launch_bounds__(256)
void k_prep(const float* __restrict__ x, const float* __restrict__ Wq,
            const float* __restrict__ Wl, const float* __restrict__ Wc,
            const float* __restrict__ Wo, u16* __restrict__ xb,
            u16* __restrict__ Wt, u16* __restrict__ xp) {
  __shared__ u16 tile[64][65];
  const int bx = blockIdx.x;
  const int t = threadIdx.x;
  if (bx < 2048) {
    const int idx = bx * 256 + t;            // < 524288 = 4194304/8
    const f4* p = (const f4*)x + (size_t)idx * 2;
    f4 a = p[0], b = p[1];
    us8 o;
    o[0] = f2bf(a[0]); o[1] = f2bf(a[1]); o[2] = f2bf(a[2]); o[3] = f2bf(a[3]);
    o[4] = f2bf(b[0]); o[5] = f2bf(b[1]); o[6] = f2bf(b[2]); o[7] = f2bf(b[3]);
    ((us8*)xb)[idx] = o;
    return;
  }
  if (bx >= 3584) {                          // x-pool: xp[b*128+j] = mean32 x rows (f32 src)
    const int row = bx - 3584;               // 0..255
    const int b = row >> 7, j = row & 127;
    const int c0 = t * 4;
    if (j == 127) { *(ui2*)&xp[(size_t)row * 1024 + c0] = ui2{0u, 0u}; return; }
    const float* src = x + ((size_t)(b * 2048 + j * 16)) * 1024 + c0;
    float s0 = 0.f, s1 = 0.f, s2 = 0.f, s3 = 0.f;
    #pragma unroll 8
    for (int r = 0; r < 32; r++) {
      f4 v = *(const f4*)(src + (size_t)r * 1024);
      s0 += v[0]; s1 += v[1]; s2 += v[2]; s3 += v[3];
    }
    const float inv = 1.f / 32.f;
    *(ui2*)&xp[(size_t)row * 1024 + c0] = pk4(s0 * inv, s1 * inv, s2 * inv, s3 * inv);
    return;
  }
  const int id = bx - 2048;                  // 0..1535
  const int n0 = (id % 96) * 64;
  const int k0 = (id / 96) * 64;
  const float* src; int ld, col0;
  if (n0 < 1024)      { src = Wq; ld = 1024; col0 = n0; }
  else if (n0 < 3072) { src = Wl; ld = 2048; col0 = n0 - 1024; }
  else if (n0 < 5120) { src = Wc; ld = 2048; col0 = n0 - 3072; }
  else                { src = Wo; ld = 1024; col0 = n0 - 5120; }
  const int r = t >> 2;          // 0..63
  const int c0 = (t & 3) * 16;   // 0,16,32,48
  const f4* sp = (const f4*)(src + (size_t)(k0 + r) * ld + col0 + c0);
  const f4 va = sp[0], vb = sp[1], vc = sp[2], vd = sp[3];
  #pragma unroll
  for (int j = 0; j < 4; j++) {
    tile[r][c0 + j]      = f2bf(va[j]);
    tile[r][c0 + 4 + j]  = f2bf(vb[j]);
    tile[r][c0 + 8 + j]  = f2bf(vc[j]);
    tile[r][c0 + 12 + j] = f2bf(vd[j]);
  }
  __syncthreads();
  us8 o0, o1;
  #pragma unroll
  for (int j = 0; j < 8; j++) { o0[j] = tile[c0 + j][r]; o1[j] = tile[c0 + 8 + j][r]; }
  u16* op = Wt + (size_t)(n0 + r) * 1024 + k0 + c0;
  *(us8*)op       = o0;
  *(us8*)(op + 8) = o1;
}

// ======= gemm1 fused: proj (id<768) + pooled proj (id>=768), flat grid 800 =======
// dbuf gl_lds 128x128 BK=64 (r8-verified structure). K=1024 for both paths.
__global__ __launch_bounds__(256)
void k_gemm1f(const u16* __restrict__ xb, const u16* __restrict__ xp,
              const u16* __restrict__ Wt, u16* __restrict__ proj,
              u16* __restrict__ C2) {
  __shared__ __align__(16) u16 LB[2][2][8192];   // [buf][A/B][128*64]
  constexpr int K = 1024;
  const int id = blockIdx.x;
  const u16 *Ab, *Bb; u16* Cb; int bm0, bn0, Nout;
  if (id < 768) {
    bm0 = (id / 24) * 128; bn0 = (id % 24) * 128;
    Ab = xb; Bb = Wt; Cb = proj; Nout = 3072;
  } else {
    const int p = id - 768;                  // 0..31
    bm0 = (p >> 4) * 128; bn0 = (p & 15) * 128;
    Ab = xp; Bb = Wt + (size_t)3072 * 1024; Cb = C2; Nout = 2048;
  }
  const int tid = threadIdx.x;
  const int wave = tid >> 6;
  const int lane = tid & 63;
  const int fr = lane & 15;
  const int g  = lane >> 4;
  const int wr = wave >> 1, wc = wave & 1;
  const int srow = lane >> 3;
  const int schunk = (lane & 7) ^ (srow & 7);
  const u16* Asrc = Ab + (size_t)(bm0 + wave * 32 + srow) * K + schunk * 8;
  const u16* Bsrc = Bb + (size_t)(bn0 + wave * 32 + srow) * K + schunk * 8;
  f4 acc[4][4] = {};
  const int KT = K >> 6;

  #pragma unroll
  for (int i = 0; i < 4; i++) {
    gl16(Asrc + (size_t)(i * 8) * K, &LB[0][0][(wave * 32 + i * 8) * 64]);
    gl16(Bsrc + (size_t)(i * 8) * K, &LB[0][1][(wave * 32 + i * 8) * 64]);
  }
  __syncthreads();

  int cur = 0;
  for (int kt = 0; kt < KT; kt++) {
    if (kt + 1 < KT) {
      const size_t go = (size_t)(kt + 1) * 64;
      #pragma unroll
      for (int i = 0; i < 4; i++) {
        gl16(Asrc + (size_t)(i * 8) * K + go, &LB[cur ^ 1][0][(wave * 32 + i * 8) * 64]);
        gl16(Bsrc + (size_t)(i * 8) * K + go, &LB[cur ^ 1][1][(wave * 32 + i * 8) * 64]);
      }
    }
    __builtin_amdgcn_sched_barrier(0);
    const u16* As = &LB[cur][0][0];
    const u16* Bs = &LB[cur][1][0];
    #pragma unroll
    for (int kh = 0; kh < 2; kh++) {
      sh8 af[4], bfv[4];
      const int ch = ((kh * 4 + g) ^ (fr & 7)) * 8;
      #pragma unroll
      for (int mi = 0; mi < 4; mi++)
        af[mi] = *(const sh8*)&As[(wr * 64 + mi * 16 + fr) * 64 + ch];
      #pragma unroll
      for (int ni = 0; ni < 4; ni++)
        bfv[ni] = *(const sh8*)&Bs[(wc * 64 + ni * 16 + fr) * 64 + ch];
      #pragma unroll
      for (int mi = 0; mi < 4; mi++)
        #pragma unroll
        for (int ni = 0; ni < 4; ni++)
          acc[mi][ni] = __builtin_amdgcn_mfma_f32_16x16x32_bf16(af[mi], bfv[ni], acc[mi][ni], 0, 0, 0);
    }
    __syncthreads();
    cur ^= 1;
  }

  const int rbase = bm0 + wr * 64 + g * 4;
  const int cbase = bn0 + wc * 64 + fr;
  #pragma unroll
  for (int mi = 0; mi < 4; mi++)
    #pragma unroll
    for (int ni = 0; ni < 4; ni++)
      #pragma unroll
      for (int r = 0; r < 4; r++)
        Cb[(size_t)(rbase + mi * 16 + r) * Nout + cbase + ni * 16] = f2bf(acc[mi][ni][r]);
}

// ======= gemm2s: (yb + yb2) @ Wo^T -> out f32, 64x64 dbuf, sum fused in A-staging =======
// B via gl_lds (r15-verified path). A: global->reg (issued at iter top, latency
// hidden under MFMA), summed bf16, ds_write to buf^1 AFTER compute (T14 split).
// Buffer hazards identical to verified dbuf: writes target buf^1 whose last
// reader closed one barrier ago; end-of-iter __syncthreads drains lgkm+vm.
__global__ __launch_bounds__(256)
void k_gemm2s(const u16* __restrict__ yb, const u16* __restrict__ yb2,
              const u16* __restrict__ Bt, float* __restrict__ Cout,
              int M, int N, int K) {
  __shared__ __align__(16) u16 LB[2][2][4096];   // [buf][A/B][64*64]
  const int bm0 = blockIdx.y * 64;
  const int bn0 = blockIdx.x * 64;
  const int tid = threadIdx.x;
  const int wave = tid >> 6;
  const int lane = tid & 63;
  const int fr = lane & 15;
  const int g  = lane >> 4;
  const int wr = wave >> 1, wc = wave & 1;
  const int srow = lane >> 3;
  const int schunk = (lane & 7) ^ (srow & 7);
  const size_t aoff = (size_t)(bm0 + wave * 16 + srow) * K + schunk * 8;
  const u16* A1 = yb  + aoff;
  const u16* A2 = yb2 + aoff;
  const u16* Bsrc = Bt + (size_t)(bn0 + wave * 16 + srow) * K + schunk * 8;
  f4 acc[2][2] = {};
  const int KT = K >> 6;

  us8 ra0, ra1, rb0, rb1;    // A-tile regs: rows wave*16+{0,8}+srow
  auto LDA = [&](int kt) {
    const size_t go = (size_t)kt * 64;
    ra0 = *(const us8*)(A1 + go);
    ra1 = *(const us8*)(A1 + (size_t)8 * K + go);
    rb0 = *(const us8*)(A2 + go);
    rb1 = *(const us8*)(A2 + (size_t)8 * K + go);
  };
  auto WRA = [&](int buf) {
    us8 s0, s1;
    #pragma unroll
    for (int j = 0; j < 8; j++) {
      s0[j] = f2bf(bf2f(ra0[j]) + bf2f(rb0[j]));
      s1[j] = f2bf(bf2f(ra1[j]) + bf2f(rb1[j]));
    }
    *(us8*)&LB[buf][0][(wave * 16) * 64 + lane * 8]     = s0;
    *(us8*)&LB[buf][0][(wave * 16 + 8) * 64 + lane * 8] = s1;
  };
  auto STB = [&](int buf, int kt) {
    const size_t go = (size_t)kt * 64;
    #pragma unroll
    for (int i = 0; i < 2; i++)
      gl16(Bsrc + (size_t)(i * 8) * K + go, &LB[buf][1][(wave * 16 + i * 8) * 64]);
  };

  // prologue: tile 0
  LDA(0);
  STB(0, 0);
  WRA(0);            // compiler waits A regs; B lands via barrier's vmcnt drain
  __syncthreads();

  int cur = 0;
  for (int kt = 0; kt < KT; kt++) {
    const bool pf = (kt + 1) < KT;
    if (pf) { LDA(kt + 1); STB(cur ^ 1, kt + 1); }
    __builtin_amdgcn_sched_barrier(0);   // keep load issue ahead of compute
    const u16* As = &LB[cur][0][0];
    const u16* Bs = &LB[cur][1][0];
    #pragma unroll
    for (int kh = 0; kh < 2; kh++) {
      sh8 af[2], bfv[2];
      const int ch = ((kh * 4 + g) ^ (fr & 7)) * 8;
      #pragma unroll
      for (int mi = 0; mi < 2; mi++)
        af[mi] = *(const sh8*)&As[(wr * 32 + mi * 16 + fr) * 64 + ch];
      #pragma unroll
      for (int ni = 0; ni < 2; ni++)
        bfv[ni] = *(const sh8*)&Bs[(wc * 32 + ni * 16 + fr) * 64 + ch];
      #pragma unroll
      for (int mi = 0; mi < 2; mi++)
        #pragma unroll
        for (int ni = 0; ni < 2; ni++)
          acc[mi][ni] = __builtin_amdgcn_mfma_f32_16x16x32_bf16(af[mi], bfv[ni], acc[mi][ni], 0, 0, 0);
    }
    if (pf) WRA(cur ^ 1);   // A regs arrived during compute; write next buf
    __syncthreads();        // drains ds_write (lgkm) + B gl16 (vm); fences bufs
    cur ^= 1;
  }

  const int rbase = bm0 + wr * 32 + g * 4;
  const int cbase = bn0 + wc * 32 + fr;
  #pragma unroll
  for (int mi = 0; mi < 2; mi++)
    #pragma unroll
    for (int ni = 0; ni < 2; ni++)
      #pragma unroll
      for (int r = 0; r < 4; r++)
        Cout[(size_t)(rbase + mi * 16 + r) * N + cbase + ni * 16] = acc[mi][ni][r];
}

// ------- fused: C2 reorg -> kpb,vpT (bx<4) | vl transpose (bx in [4,36)) -------
// C2[256 rows=b*128+j][2048 cols = kc_pool(0..1023) | vc_pool(1024..2047)]
__global__ __launch_bounds__(256)
void k_poolvt(const u16* __restrict__ proj, const u16* __restrict__ C2,
              u16* __restrict__ kpb, u16* __restrict__ vpT, u16* __restrict__ vlT) {
  __shared__ u16 tile[64][72];
  const int bx = blockIdx.x;
  const int bh = blockIdx.y;
  const int b = bh >> 4, h = bh & 15;
  const int t = threadIdx.x;
  if (bx < 4) {
    const int d = t & 63;
    const int jj = t >> 6;             // 0..3
    #pragma unroll
    for (int j0 = 0; j0 < 8; j0++) {
      const int j = bx * 32 + jj * 8 + j0;    // 0..127 (row 127 = zeros from xp pad)
      const size_t crow = (size_t)(b * 128 + j) * 2048;
      kpb[((size_t)bh * 128 + j) * 64 + d] = C2[crow + h * 64 + d];
      vpT[((size_t)bh * 64 + d) * 128 + j] = C2[crow + 1024 + h * 64 + d];
    }
    return;
  }
  const int tt = bx - 4;               // 0..31 token tile
  const int r = t >> 2;                // 0..63
  const int c0 = (t & 3) * 16;
  const u16* sp = proj + (size_t)(b * 2048 + tt * 64 + r) * 3072 + 2048 + h * 64 + c0;
  us8 v0 = *(const us8*)sp;
  us8 v1 = *(const us8*)(sp + 8);
  #pragma unroll
  for (int jj = 0; jj < 8; jj++) { tile[r][c0 + jj] = v0[jj]; tile[r][c0 + 8 + jj] = v1[jj]; }
  __syncthreads();
  u16* op = vlT + ((size_t)bh * 64 + r) * 2048 + tt * 64 + c0;
  #pragma unroll
  for (int jj = 0; jj < 16; jj++) op[jj] = tile[c0 + jj][r];
}

// -------- fused attention: bx<32 local -> yb, bx>=32 comp -> yb2 (concurrent) --------
// proj layout [4096][3072]: q(0) | kl(1024) | vl(2048)
__global__ __launch_bounds__(256)
void k_attn(const u16* __restrict__ proj, const u16* __restrict__ vlT,
            const u16* __restrict__ kpb, const u16* __restrict__ vpT,
            u16* __restrict__ yb, u16* __restrict__ yb2) {
  __shared__ __align__(16) u16 SB[26688];   // 53376 B -> 3 blocks/CU
  const int bx = blockIdx.x;
  const int bh = blockIdx.y;
  const int b = bh >> 4, h = bh & 15;
  const int tid = threadIdx.x;
  const int wave = tid >> 6;
  const int lane = tid & 63;
  const int fr = lane & 15;
  const int g  = lane >> 4;
  const int ko = g * 8;
  const u16* prow = proj + (size_t)(b * 2048) * 3072;

  if (bx < 32) {
    // ================= LOCAL =================
    const int qt = bx;
    const int q0 = qt * 64;
    const int wq0 = q0 + wave * 16;
    const int i_abs = wq0 + fr;
    const u16* klb = prow + 1024 + h * 64;
    const u16* vltb = vlT + (size_t)bh * 64 * 2048;

    #pragma unroll
    for (int it = 0; it < 7; it++) {
      const int inst = it * 4 + wave;
      if (inst < 27) {
        const int c = inst * 64 + lane;
        const int row = c / 9;
        const int sl = c - row * 9;
        int jg = q0 - 128 + row; if (jg < 0) jg = 0;
        gl16(klb + (size_t)jg * 3072 + (sl & 7) * 8, &SB[inst * 512]);
      }
    }
    #pragma unroll
    for (int it = 0; it < 7; it++) {
      const int inst = it * 4 + wave;
      if (inst < 25) {
        const int c = inst * 64 + lane;
        const int row = c / 25;
        const int sl = c - row * 25;
        int tc = q0 - 128 + (sl < 24 ? sl : 0) * 8; if (tc < 0) tc = 0;
        gl16(vltb + (size_t)row * 2048 + tc, &SB[13824 + inst * 512]);
      }
    }
    const sh8 bq0 = *(const sh8*)(prow + (size_t)i_abs * 3072 + h * 64 + ko);
    const sh8 bq1 = *(const sh8*)(prow + (size_t)i_abs * 3072 + h * 64 + 32 + ko);
    __syncthreads();   // barrier 1

    f4 st[9];
    #pragma unroll
    for (int f = 0; f < 9; f++) st[f] = f4{0.f, 0.f, 0.f, 0.f};
    #pragma unroll
    for (int kh = 0; kh < 2; kh++) {
      const sh8 bq = kh ? bq1 : bq0;
      #pragma unroll
      for (int f = 0; f < 9; f++) {
        sh8 ak = *(const sh8*)&SB[(wave * 16 + f * 16 + fr) * 72 + kh * 32 + ko];
        st[f] = __builtin_amdgcn_mfma_f32_16x16x32_bf16(ak, bq, st[f], 0, 0, 0);
      }
    }
    const int klo = 128 - wq0;
    float m = -1e30f;
    #pragma unroll
    for (int f = 0; f < 9; f++)
      #pragma unroll
      for (int r = 0; r < 4; r++) {
        const int kk = f * 16 + g * 4 + r;
        const bool ok = (kk > fr) && (kk <= fr + 128) && (kk >= klo);
        const float v = ok ? st[f][r] * 0.125f : -1e30f;
        st[f][r] = v; m = fmaxf(m, v);
      }
    m = fmaxf(m, __shfl_xor(m, 16));
    m = fmaxf(m, __shfl_xor(m, 32));
    float l = 0.f;
    #pragma unroll
    for (int f = 0; f < 9; f++)
      #pragma unroll
      for (int r = 0; r < 4; r++) {
        const float p = __expf(st[f][r] - m);
        st[f][r] = p; l += p;
      }
    l += __shfl_xor(l, 16);
    l += __shfl_xor(l, 32);
    const float inv = 1.f / l;

    __syncthreads();   // barrier 2: KL region becomes P

    u16* Pw = &SB[wave * 2688];     // [16][168]
    #pragma unroll
    for (int f = 0; f < 9; f++)
      *(ui2*)&Pw[fr * 168 + f * 16 + g * 4] =
          pk4(st[f][0] * inv, st[f][1] * inv, st[f][2] * inv, st[f][3] * inv);
    *(ui2*)&Pw[fr * 168 + 144 + g * 4] = ui2{0u, 0u};

    f4 yacc[4];
    #pragma unroll
    for (int ni = 0; ni < 4; ni++) yacc[ni] = f4{0.f, 0.f, 0.f, 0.f};
    #pragma unroll
    for (int ks = 0; ks < 5; ks++) {
      sh8 pa = *(const sh8*)&Pw[fr * 168 + ks * 32 + ko];
      const int col = wave * 16 + ks * 32 + ko;
      #pragma unroll
      for (int ni = 0; ni < 4; ni++) {
        sh8 vb = *(const sh8*)&SB[13824 + (ni * 16 + fr) * 200 + col];
        yacc[ni] = __builtin_amdgcn_mfma_f32_16x16x32_bf16(pa, vb, yacc[ni], 0, 0, 0);
      }
    }

    #pragma unroll
    for (int ni = 0; ni < 4; ni++)
      #pragma unroll
      for (int r = 0; r < 4; r++)
        Pw[(4 * g + r) * 72 + ni * 16 + fr] = f2bf(yacc[ni][r]);
    const int row = lane >> 2;
    const int c0 = (lane & 3) * 16;
    u16* gy = yb + (size_t)(b * 2048 + wq0 + row) * 1024 + h * 64 + c0;
    *(us8*)gy       = *(const us8*)&Pw[row * 72 + c0];
    *(us8*)(gy + 8) = *(const us8*)&Pw[row * 72 + c0 + 8];
    return;
  }

  // ================= COMPRESSED =================
  const int qt = bx - 32;
  const int wq0 = qt * 64 + wave * 16;
  const int i_abs = wq0 + fr;
  const u16* kpr = kpb + (size_t)bh * 8192;
  const u16* vptb = vpT + (size_t)bh * 8192;

  #pragma unroll
  for (int it = 0; it < 5; it++) {
    const int inst = it * 4 + wave;
    if (inst < 18) {
      const int c = inst * 64 + lane;
      const int row = c / 9;
      const int sl = c - row * 9;
      gl16(kpr + (size_t)row * 64 + (sl & 7) * 8, &SB[inst * 512]);
    }
  }
  #pragma unroll
  for (int it = 0; it < 5; it++) {
    const int inst = it * 4 + wave;
    if (inst < 17) {
      const int c = inst * 64 + lane;
      const int row = c / 17;
      const int sl = c - row * 17;
      gl16(vptb + (size_t)row * 128 + (sl & 15) * 8, &SB[9216 + inst * 512]);
    }
  }
  const sh8 bq0 = *(const sh8*)(prow + (size_t)i_abs * 3072 + h * 64 + ko);
  const sh8 bq1 = *(const sh8*)(prow + (size_t)i_abs * 3072 + h * 64 + 32 + ko);
  const int yrow = lane >> 2;
  const int yc0 = (lane & 3) * 16;
  __syncthreads();   // barrier 1

  const int nf = ((wq0 + 15) >> 8) + 1;   // 1..8, wave-uniform
  f4 sc[8];
  #pragma unroll
  for (int f = 0; f < 8; f++) sc[f] = f4{0.f, 0.f, 0.f, 0.f};
  #pragma unroll
  for (int kh = 0; kh < 2; kh++) {
    const sh8 bq = kh ? bq1 : bq0;
    #pragma unroll
    for (int f = 0; f < 8; f++)
      if (f < nf) {
        sh8 ak = *(const sh8*)&SB[(f * 16 + fr) * 72 + kh * 32 + ko];
        sc[f] = __builtin_amdgcn_mfma_f32_16x16x32_bf16(ak, bq, sc[f], 0, 0, 0);
      }
  }
  float m2 = -1e30f;
  #pragma unroll
  for (int f = 0; f < 8; f++)
    #pragma unroll
    for (int r = 0; r < 4; r++) {
      const int jj = f * 16 + g * 4 + r;
      const bool ok = (jj <= 126) && (16 * jj <= i_abs);
      const float v = ok ? sc[f][r] * 0.125f : -1e30f;
      sc[f][r] = v; m2 = fmaxf(m2, v);
    }
  m2 = fmaxf(m2, __shfl_xor(m2, 16));
  m2 = fmaxf(m2, __shfl_xor(m2, 32));
  float l2 = 0.f;
  #pragma unroll
  for (int f = 0; f < 8; f++)
    #pragma unroll
    for (int r = 0; r < 4; r++) {
      const float p = __expf(sc[f][r] - m2);
      sc[f][r] = p; l2 += p;
    }
  l2 += __shfl_xor(l2, 16);
  l2 += __shfl_xor(l2, 32);
  const float inv2 = 1.f / l2;

  __syncthreads();   // barrier 2: KC region becomes P

  u16* Pw = &SB[wave * 2176];     // [16][136]
  #pragma unroll
  for (int f = 0; f < 8; f++)
    if (f < nf)
      *(ui2*)&Pw[fr * 136 + f * 16 + g * 4] =
          pk4(sc[f][0] * inv2, sc[f][1] * inv2, sc[f][2] * inv2, sc[f][3] * inv2);
  if (nf & 1)
    *(ui2*)&Pw[fr * 136 + nf * 16 + g * 4] = ui2{0u, 0u};

  f4 yacc[4];
  #pragma unroll
  for (int ni = 0; ni < 4; ni++) yacc[ni] = f4{0.f, 0.f, 0.f, 0.f};
  const int nks = (nf + 1) >> 1;
  #pragma unroll
  for (int ks = 0; ks < 4; ks++)
    if (ks < nks) {
      sh8 pa = *(const sh8*)&Pw[fr * 136 + ks * 32 + ko];
      #pragma unroll
      for (int ni = 0; ni < 4; ni++) {
        sh8 vb = *(const sh8*)&SB[9216 + (ni * 16 + fr) * 136 + ks * 32 + ko];
        yacc[ni] = __builtin_amdgcn_mfma_f32_16x16x32_bf16(pa, vb, yacc[ni], 0, 0, 0);
      }
    }

  #pragma unroll
  for (int ni = 0; ni < 4; ni++)
    #pragma unroll
    for (int r = 0; r < 4; r++)
      Pw[(4 * g + r) * 72 + ni * 16 + fr] = f2bf(yacc[ni][r]);
  u16* gy = yb2 + (size_t)(b * 2048 + wq0 + yrow) * 1024 + h * 64 + yc0;
  *(us8*)gy       = *(const us8*)&Pw[yrow * 72 + yc0];
  *(us8*)(gy + 8) = *(const us8*)&Pw[yrow * 72 + yc0 + 8];
}

extern "C" void kernel_launch(void* const* d_in, const int* in_sizes, int n_in,
                              void* d_out, int out_size, void* d_ws, size_t ws_size,
                              hipStream_t stream) {
  const float* x  = (const float*)d_in[0];
  const float* Wq = (const float*)d_in[1];
  const float* Wl = (const float*)d_in[2];
  const float* Wc = (const float*)d_in[3];
  const float* Wo = (const float*)d_in[4];
  // dkc/dvc unused: n_def == 0 at T=2048.
  float* out = (float*)d_out;
  char* ws = (char*)d_ws;
  // workspace (~65.5 MB): vlT aliases xb (xb dead after gemm1f)
  u16* xb   = (u16*)(ws);                       //  8 MB  x bf16 [4096][1024]
  u16* vlT  = (u16*)(ws);                       //  8 MB  vl^T bf16 [32][64][2048] (after gemm1f)
  u16* Wt   = (u16*)(ws + 8388608);             // 12 MB  weights^T bf16 [6144][1024]
  u16* proj = (u16*)(ws + 20971520);            // 24 MB  [4096][3072] q|kl|vl bf16
  u16* xp   = (u16*)(ws + 46137344);            // 512 KB pooled x bf16 [256][1024]
  u16* C2   = (u16*)(ws + 46661632);            //  1 MB  pooled proj bf16 [256][2048]
  u16* kpb  = (u16*)(ws + 47710208);            // 512 KB pooled K bf16 [32][128][64]
  u16* vpT  = (u16*)(ws + 48234496);            // 512 KB pooled V^T bf16 [32][64][128]
  u16* yb   = (u16*)(ws + 48758784);            //  8 MB  y_local bf16 [4096][1024]
  u16* yb2  = (u16*)(ws + 57147392);            //  8 MB  y_comp  bf16 [4096][1024]

  k_prep<<<3840, 256, 0, stream>>>(x, Wq, Wl, Wc, Wo, xb, Wt, xp);
  k_gemm1f<<<800, 256, 0, stream>>>(xb, xp, Wt, proj, C2);
  k_poolvt<<<dim3(36, 32), 256, 0, stream>>>(proj, C2, kpb, vpT, vlT);
  k_attn<<<dim3(64, 32), 256, 0, stream>>>(proj, vlT, kpb, vpT, yb, yb2);
  k_gemm2s<<<dim3(16, 64), 256, 0, stream>>>(yb, yb2, Wt + (size_t)5120 * 1024, out, 4096, 1024, 1024);
}

// Round 20
// 111.279 us; speedup vs baseline: 1.0536x; 1.0471x over previous
//
#include <hip/hip_runtime.h>

typedef unsigned short u16;
typedef unsigned int u32;
typedef __attribute__((ext_vector_type(8))) short sh8;           // 8 bf16 (4 VGPR)
typedef __attribute__((ext_vector_type(8))) unsigned short us8;
typedef __attribute__((ext_vector_type(2))) unsigned int ui2;
typedef __attribute__((ext_vector_type(4))) float f4;

__device__ __forceinline__ float bf2f(u16 u) {
  union { unsigned u; float f; } v; v.u = ((unsigned)u) << 16; return v.f;
}
__device__ __forceinline__ u16 f2bf(float f) {
  union { float f; unsigned u; } v; v.f = f;
  unsigned r = v.u + 0x7fffu + ((v.u >> 16) & 1u);   // RNE, inputs finite
  return (u16)(r >> 16);
}
// pack 4 f32 -> 4 bf16 (RNE) in 2 insts
__device__ __forceinline__ ui2 pk4(float a, float b, float c, float d) {
  u32 lo, hi;
  asm("v_cvt_pk_bf16_f32 %0, %1, %2" : "=v"(lo) : "v"(a), "v"(b));
  asm("v_cvt_pk_bf16_f32 %0, %1, %2" : "=v"(hi) : "v"(c), "v"(d));
  ui2 r; r[0] = lo; r[1] = hi; return r;
}
// async global->LDS, 16B per lane; dest = wave-uniform base + lane*16
__device__ __forceinline__ void gl16(const void* g, void* l) {
  __builtin_amdgcn_global_load_lds(
      (const __attribute__((address_space(1))) unsigned int*)g,
      (__attribute__((address_space(3))) unsigned int*)l, 16, 0, 0);
}

// ---- fused: f32->bf16 cvt (bx<2048) | weight transpose (2048..3583) | x-pool (>=3584) ----
// Wt rows: [0,1024)=Wq | [1024,3072)=Wl | [3072,5120)=Wc | [5120,6144)=Wo
__global__ __launch_bounds__(256)
void k_prep(const float* __restrict__ x, const float* __restrict__ Wq,
            const float* __restrict__ Wl, const float* __restrict__ Wc,
            const float* __restrict__ Wo, u16* __restrict__ xb,
            u16* __restrict__ Wt, u16* __restrict__ xp) {
  __shared__ u16 tile[64][65];
  const int bx = blockIdx.x;
  const int t = threadIdx.x;
  if (bx < 2048) {
    const int idx = bx * 256 + t;            // < 524288 = 4194304/8
    const f4* p = (const f4*)x + (size_t)idx * 2;
    f4 a = p[0], b = p[1];
    us8 o;
    o[0] = f2bf(a[0]); o[1] = f2bf(a[1]); o[2] = f2bf(a[2]); o[3] = f2bf(a[3]);
    o[4] = f2bf(b[0]); o[5] = f2bf(b[1]); o[6] = f2bf(b[2]); o[7] = f2bf(b[3]);
    ((us8*)xb)[idx] = o;
    return;
  }
  if (bx >= 3584) {                          // x-pool: xp[b*128+j] = mean32 x rows (f32 src)
    const int row = bx - 3584;               // 0..255
    const int b = row >> 7, j = row & 127;
    const int c0 = t * 4;
    if (j == 127) { *(ui2*)&xp[(size_t)row * 1024 + c0] = ui2{0u, 0u}; return; }
    const float* src = x + ((size_t)(b * 2048 + j * 16)) * 1024 + c0;
    float s0 = 0.f, s1 = 0.f, s2 = 0.f, s3 = 0.f;
    #pragma unroll 8
    for (int r = 0; r < 32; r++) {
      f4 v = *(const f4*)(src + (size_t)r * 1024);
      s0 += v[0]; s1 += v[1]; s2 += v[2]; s3 += v[3];
    }
    const float inv = 1.f / 32.f;
    *(ui2*)&xp[(size_t)row * 1024 + c0] = pk4(s0 * inv, s1 * inv, s2 * inv, s3 * inv);
    return;
  }
  const int id = bx - 2048;                  // 0..1535
  const int n0 = (id % 96) * 64;
  const int k0 = (id / 96) * 64;
  const float* src; int ld, col0;
  if (n0 < 1024)      { src = Wq; ld = 1024; col0 = n0; }
  else if (n0 < 3072) { src = Wl; ld = 2048; col0 = n0 - 1024; }
  else if (n0 < 5120) { src = Wc; ld = 2048; col0 = n0 - 3072; }
  else                { src = Wo; ld = 1024; col0 = n0 - 5120; }
  const int r = t >> 2;          // 0..63
  const int c0 = (t & 3) * 16;   // 0,16,32,48
  const f4* sp = (const f4*)(src + (size_t)(k0 + r) * ld + col0 + c0);
  const f4 va = sp[0], vb = sp[1], vc = sp[2], vd = sp[3];
  #pragma unroll
  for (int j = 0; j < 4; j++) {
    tile[r][c0 + j]      = f2bf(va[j]);
    tile[r][c0 + 4 + j]  = f2bf(vb[j]);
    tile[r][c0 + 8 + j]  = f2bf(vc[j]);
    tile[r][c0 + 12 + j] = f2bf(vd[j]);
  }
  __syncthreads();
  us8 o0, o1;
  #pragma unroll
  for (int j = 0; j < 8; j++) { o0[j] = tile[c0 + j][r]; o1[j] = tile[c0 + 8 + j][r]; }
  u16* op = Wt + (size_t)(n0 + r) * 1024 + k0 + c0;
  *(us8*)op       = o0;
  *(us8*)(op + 8) = o1;
}

// ======= gemm1 fused: proj (id<768) + pooled proj (id>=768), flat grid 800 =======
// dbuf gl_lds 128x128 BK=64 (r8-verified structure). K=1024 for both paths.
__global__ __launch_bounds__(256)
void k_gemm1f(const u16* __restrict__ xb, const u16* __restrict__ xp,
              const u16* __restrict__ Wt, u16* __restrict__ proj,
              u16* __restrict__ C2) {
  __shared__ __align__(16) u16 LB[2][2][8192];   // [buf][A/B][128*64]
  constexpr int K = 1024;
  const int id = blockIdx.x;
  const u16 *Ab, *Bb; u16* Cb; int bm0, bn0, Nout;
  if (id < 768) {
    bm0 = (id / 24) * 128; bn0 = (id % 24) * 128;
    Ab = xb; Bb = Wt; Cb = proj; Nout = 3072;
  } else {
    const int p = id - 768;                  // 0..31
    bm0 = (p >> 4) * 128; bn0 = (p & 15) * 128;
    Ab = xp; Bb = Wt + (size_t)3072 * 1024; Cb = C2; Nout = 2048;
  }
  const int tid = threadIdx.x;
  const int wave = tid >> 6;
  const int lane = tid & 63;
  const int fr = lane & 15;
  const int g  = lane >> 4;
  const int wr = wave >> 1, wc = wave & 1;
  const int srow = lane >> 3;
  const int schunk = (lane & 7) ^ (srow & 7);
  const u16* Asrc = Ab + (size_t)(bm0 + wave * 32 + srow) * K + schunk * 8;
  const u16* Bsrc = Bb + (size_t)(bn0 + wave * 32 + srow) * K + schunk * 8;
  f4 acc[4][4] = {};
  const int KT = K >> 6;

  #pragma unroll
  for (int i = 0; i < 4; i++) {
    gl16(Asrc + (size_t)(i * 8) * K, &LB[0][0][(wave * 32 + i * 8) * 64]);
    gl16(Bsrc + (size_t)(i * 8) * K, &LB[0][1][(wave * 32 + i * 8) * 64]);
  }
  __syncthreads();

  int cur = 0;
  for (int kt = 0; kt < KT; kt++) {
    if (kt + 1 < KT) {
      const size_t go = (size_t)(kt + 1) * 64;
      #pragma unroll
      for (int i = 0; i < 4; i++) {
        gl16(Asrc + (size_t)(i * 8) * K + go, &LB[cur ^ 1][0][(wave * 32 + i * 8) * 64]);
        gl16(Bsrc + (size_t)(i * 8) * K + go, &LB[cur ^ 1][1][(wave * 32 + i * 8) * 64]);
      }
    }
    __builtin_amdgcn_sched_barrier(0);
    const u16* As = &LB[cur][0][0];
    const u16* Bs = &LB[cur][1][0];
    #pragma unroll
    for (int kh = 0; kh < 2; kh++) {
      sh8 af[4], bfv[4];
      const int ch = ((kh * 4 + g) ^ (fr & 7)) * 8;
      #pragma unroll
      for (int mi = 0; mi < 4; mi++)
        af[mi] = *(const sh8*)&As[(wr * 64 + mi * 16 + fr) * 64 + ch];
      #pragma unroll
      for (int ni = 0; ni < 4; ni++)
        bfv[ni] = *(const sh8*)&Bs[(wc * 64 + ni * 16 + fr) * 64 + ch];
      #pragma unroll
      for (int mi = 0; mi < 4; mi++)
        #pragma unroll
        for (int ni = 0; ni < 4; ni++)
          acc[mi][ni] = __builtin_amdgcn_mfma_f32_16x16x32_bf16(af[mi], bfv[ni], acc[mi][ni], 0, 0, 0);
    }
    __syncthreads();
    cur ^= 1;
  }

  const int rbase = bm0 + wr * 64 + g * 4;
  const int cbase = bn0 + wc * 64 + fr;
  #pragma unroll
  for (int mi = 0; mi < 4; mi++)
    #pragma unroll
    for (int ni = 0; ni < 4; ni++)
      #pragma unroll
      for (int r = 0; r < 4; r++)
        Cb[(size_t)(rbase + mi * 16 + r) * Nout + cbase + ni * 16] = f2bf(acc[mi][ni][r]);
}

// ======= gemm2: dbuf gl_lds, 64x64 tile, grid 16x64 = 1024 blocks (r15-verified) =======
__global__ __launch_bounds__(256)
void k_gemm2(const u16* __restrict__ A, const u16* __restrict__ Bt,
             float* __restrict__ Cout, int M, int N, int K) {
  __shared__ __align__(16) u16 LB[2][2][4096];   // [buf][A/B][64*64]
  const int bm0 = blockIdx.y * 64;
  const int bn0 = blockIdx.x * 64;
  const int tid = threadIdx.x;
  const int wave = tid >> 6;
  const int lane = tid & 63;
  const int fr = lane & 15;
  const int g  = lane >> 4;
  const int wr = wave >> 1, wc = wave & 1;
  const int srow = lane >> 3;
  const int schunk = (lane & 7) ^ (srow & 7);
  const u16* Asrc = A  + (size_t)(bm0 + wave * 16 + srow) * K + schunk * 8;
  const u16* Bsrc = Bt + (size_t)(bn0 + wave * 16 + srow) * K + schunk * 8;
  f4 acc[2][2] = {};
  const int KT = K >> 6;

  #pragma unroll
  for (int i = 0; i < 2; i++) {
    gl16(Asrc + (size_t)(i * 8) * K, &LB[0][0][(wave * 16 + i * 8) * 64]);
    gl16(Bsrc + (size_t)(i * 8) * K, &LB[0][1][(wave * 16 + i * 8) * 64]);
  }
  __syncthreads();

  int cur = 0;
  for (int kt = 0; kt < KT; kt++) {
    if (kt + 1 < KT) {
      const size_t go = (size_t)(kt + 1) * 64;
      #pragma unroll
      for (int i = 0; i < 2; i++) {
        gl16(Asrc + (size_t)(i * 8) * K + go, &LB[cur ^ 1][0][(wave * 16 + i * 8) * 64]);
        gl16(Bsrc + (size_t)(i * 8) * K + go, &LB[cur ^ 1][1][(wave * 16 + i * 8) * 64]);
      }
    }
    __builtin_amdgcn_sched_barrier(0);   // keep prefetch issue ahead of compute
    const u16* As = &LB[cur][0][0];
    const u16* Bs = &LB[cur][1][0];
    #pragma unroll
    for (int kh = 0; kh < 2; kh++) {
      sh8 af[2], bfv[2];
      const int ch = ((kh * 4 + g) ^ (fr & 7)) * 8;
      #pragma unroll
      for (int mi = 0; mi < 2; mi++)
        af[mi] = *(const sh8*)&As[(wr * 32 + mi * 16 + fr) * 64 + ch];
      #pragma unroll
      for (int ni = 0; ni < 2; ni++)
        bfv[ni] = *(const sh8*)&Bs[(wc * 32 + ni * 16 + fr) * 64 + ch];
      #pragma unroll
      for (int mi = 0; mi < 2; mi++)
        #pragma unroll
        for (int ni = 0; ni < 2; ni++)
          acc[mi][ni] = __builtin_amdgcn_mfma_f32_16x16x32_bf16(af[mi], bfv[ni], acc[mi][ni], 0, 0, 0);
    }
    __syncthreads();   // drains vmcnt (prefetch landed) + lgkmcnt
    cur ^= 1;
  }

  const int rbase = bm0 + wr * 32 + g * 4;
  const int cbase = bn0 + wc * 32 + fr;
  #pragma unroll
  for (int mi = 0; mi < 2; mi++)
    #pragma unroll
    for (int ni = 0; ni < 2; ni++)
      #pragma unroll
      for (int r = 0; r < 4; r++)
        Cout[(size_t)(rbase + mi * 16 + r) * N + cbase + ni * 16] = acc[mi][ni][r];
}

// ------- fused: C2 reorg -> kpb,vpT (bx<4) | vl transpose (bx in [4,36)) -------
// C2[256 rows=b*128+j][2048 cols = kc_pool(0..1023) | vc_pool(1024..2047)]
__global__ __launch_bounds__(256)
void k_poolvt(const u16* __restrict__ proj, const u16* __restrict__ C2,
              u16* __restrict__ kpb, u16* __restrict__ vpT, u16* __restrict__ vlT) {
  __shared__ u16 tile[64][72];
  const int bx = blockIdx.x;
  const int bh = blockIdx.y;
  const int b = bh >> 4, h = bh & 15;
  const int t = threadIdx.x;
  if (bx < 4) {
    const int d = t & 63;
    const int jj = t >> 6;             // 0..3
    #pragma unroll
    for (int j0 = 0; j0 < 8; j0++) {
      const int j = bx * 32 + jj * 8 + j0;    // 0..127 (row 127 = zeros from xp pad)
      const size_t crow = (size_t)(b * 128 + j) * 2048;
      kpb[((size_t)bh * 128 + j) * 64 + d] = C2[crow + h * 64 + d];
      vpT[((size_t)bh * 64 + d) * 128 + j] = C2[crow + 1024 + h * 64 + d];
    }
    return;
  }
  const int tt = bx - 4;               // 0..31 token tile
  const int r = t >> 2;                // 0..63
  const int c0 = (t & 3) * 16;
  const u16* sp = proj + (size_t)(b * 2048 + tt * 64 + r) * 3072 + 2048 + h * 64 + c0;
  us8 v0 = *(const us8*)sp;
  us8 v1 = *(const us8*)(sp + 8);
  #pragma unroll
  for (int jj = 0; jj < 8; jj++) { tile[r][c0 + jj] = v0[jj]; tile[r][c0 + 8 + jj] = v1[jj]; }
  __syncthreads();
  u16* op = vlT + ((size_t)bh * 64 + r) * 2048 + tt * 64 + c0;
  #pragma unroll
  for (int jj = 0; jj < 16; jj++) op[jj] = tile[c0 + jj][r];
}

// -------- fused attention: bx<32 local -> yb, bx>=32 comp -> yb2 (concurrent) --------
// proj layout [4096][3072]: q(0) | kl(1024) | vl(2048)
__global__ __launch_bounds__(256)
void k_attn(const u16* __restrict__ proj, const u16* __restrict__ vlT,
            const u16* __restrict__ kpb, const u16* __restrict__ vpT,
            u16* __restrict__ yb, u16* __restrict__ yb2) {
  __shared__ __align__(16) u16 SB[26688];   // 53376 B -> 3 blocks/CU
  const int bx = blockIdx.x;
  const int bh = blockIdx.y;
  const int b = bh >> 4, h = bh & 15;
  const int tid = threadIdx.x;
  const int wave = tid >> 6;
  const int lane = tid & 63;
  const int fr = lane & 15;
  const int g  = lane >> 4;
  const int ko = g * 8;
  const u16* prow = proj + (size_t)(b * 2048) * 3072;

  if (bx < 32) {
    // ================= LOCAL =================
    const int qt = bx;
    const int q0 = qt * 64;
    const int wq0 = q0 + wave * 16;
    const int i_abs = wq0 + fr;
    const u16* klb = prow + 1024 + h * 64;
    const u16* vltb = vlT + (size_t)bh * 64 * 2048;

    #pragma unroll
    for (int it = 0; it < 7; it++) {
      const int inst = it * 4 + wave;
      if (inst < 27) {
        const int c = inst * 64 + lane;
        const int row = c / 9;
        const int sl = c - row * 9;
        int jg = q0 - 128 + row; if (jg < 0) jg = 0;
        gl16(klb + (size_t)jg * 3072 + (sl & 7) * 8, &SB[inst * 512]);
      }
    }
    #pragma unroll
    for (int it = 0; it < 7; it++) {
      const int inst = it * 4 + wave;
      if (inst < 25) {
        const int c = inst * 64 + lane;
        const int row = c / 25;
        const int sl = c - row * 25;
        int tc = q0 - 128 + (sl < 24 ? sl : 0) * 8; if (tc < 0) tc = 0;
        gl16(vltb + (size_t)row * 2048 + tc, &SB[13824 + inst * 512]);
      }
    }
    const sh8 bq0 = *(const sh8*)(prow + (size_t)i_abs * 3072 + h * 64 + ko);
    const sh8 bq1 = *(const sh8*)(prow + (size_t)i_abs * 3072 + h * 64 + 32 + ko);
    __syncthreads();   // barrier 1

    f4 st[9];
    #pragma unroll
    for (int f = 0; f < 9; f++) st[f] = f4{0.f, 0.f, 0.f, 0.f};
    #pragma unroll
    for (int kh = 0; kh < 2; kh++) {
      const sh8 bq = kh ? bq1 : bq0;
      #pragma unroll
      for (int f = 0; f < 9; f++) {
        sh8 ak = *(const sh8*)&SB[(wave * 16 + f * 16 + fr) * 72 + kh * 32 + ko];
        st[f] = __builtin_amdgcn_mfma_f32_16x16x32_bf16(ak, bq, st[f], 0, 0, 0);
      }
    }
    const int klo = 128 - wq0;
    float m = -1e30f;
    #pragma unroll
    for (int f = 0; f < 9; f++)
      #pragma unroll
      for (int r = 0; r < 4; r++) {
        const int kk = f * 16 + g * 4 + r;
        const bool ok = (kk > fr) && (kk <= fr + 128) && (kk >= klo);
        const float v = ok ? st[f][r] * 0.125f : -1e30f;
        st[f][r] = v; m = fmaxf(m, v);
      }
    m = fmaxf(m, __shfl_xor(m, 16));
    m = fmaxf(m, __shfl_xor(m, 32));
    float l = 0.f;
    #pragma unroll
    for (int f = 0; f < 9; f++)
      #pragma unroll
      for (int r = 0; r < 4; r++) {
        const float p = __expf(st[f][r] - m);
        st[f][r] = p; l += p;
      }
    l += __shfl_xor(l, 16);
    l += __shfl_xor(l, 32);
    const float inv = 1.f / l;

    __syncthreads();   // barrier 2: KL region becomes P

    u16* Pw = &SB[wave * 2688];     // [16][168]
    #pragma unroll
    for (int f = 0; f < 9; f++)
      *(ui2*)&Pw[fr * 168 + f * 16 + g * 4] =
          pk4(st[f][0] * inv, st[f][1] * inv, st[f][2] * inv, st[f][3] * inv);
    *(ui2*)&Pw[fr * 168 + 144 + g * 4] = ui2{0u, 0u};

    f4 yacc[4];
    #pragma unroll
    for (int ni = 0; ni < 4; ni++) yacc[ni] = f4{0.f, 0.f, 0.f, 0.f};
    #pragma unroll
    for (int ks = 0; ks < 5; ks++) {
      sh8 pa = *(const sh8*)&Pw[fr * 168 + ks * 32 + ko];
      int col = wave * 16 + ks * 32 + ko;
      if (col > 192) col = 192;   // P=0 beyond 192-key window; clamp keeps the
                                  // 16B read inside the written [64][200] row
                                  // (fixes stale-LDS 0*NaN hazard, r16/r19 fails)
      #pragma unroll
      for (int ni = 0; ni < 4; ni++) {
        sh8 vb = *(const sh8*)&SB[13824 + (ni * 16 + fr) * 200 + col];
        yacc[ni] = __builtin_amdgcn_mfma_f32_16x16x32_bf16(pa, vb, yacc[ni], 0, 0, 0);
      }
    }

    #pragma unroll
    for (int ni = 0; ni < 4; ni++)
      #pragma unroll
      for (int r = 0; r < 4; r++)
        Pw[(4 * g + r) * 72 + ni * 16 + fr] = f2bf(yacc[ni][r]);
    const int row = lane >> 2;
    const int c0 = (lane & 3) * 16;
    u16* gy = yb + (size_t)(b * 2048 + wq0 + row) * 1024 + h * 64 + c0;
    *(us8*)gy       = *(const us8*)&Pw[row * 72 + c0];
    *(us8*)(gy + 8) = *(const us8*)&Pw[row * 72 + c0 + 8];
    return;
  }

  // ================= COMPRESSED =================
  const int qt = bx - 32;
  const int wq0 = qt * 64 + wave * 16;
  const int i_abs = wq0 + fr;
  const u16* kpr = kpb + (size_t)bh * 8192;
  const u16* vptb = vpT + (size_t)bh * 8192;

  #pragma unroll
  for (int it = 0; it < 5; it++) {
    const int inst = it * 4 + wave;
    if (inst < 18) {
      const int c = inst * 64 + lane;
      const int row = c / 9;
      const int sl = c - row * 9;
      gl16(kpr + (size_t)row * 64 + (sl & 7) * 8, &SB[inst * 512]);
    }
  }
  #pragma unroll
  for (int it = 0; it < 5; it++) {
    const int inst = it * 4 + wave;
    if (inst < 17) {
      const int c = inst * 64 + lane;
      const int row = c / 17;
      const int sl = c - row * 17;
      gl16(vptb + (size_t)row * 128 + (sl & 15) * 8, &SB[9216 + inst * 512]);
    }
  }
  const sh8 bq0 = *(const sh8*)(prow + (size_t)i_abs * 3072 + h * 64 + ko);
  const sh8 bq1 = *(const sh8*)(prow + (size_t)i_abs * 3072 + h * 64 + 32 + ko);
  const int yrow = lane >> 2;
  const int yc0 = (lane & 3) * 16;
  __syncthreads();   // barrier 1

  const int nf = ((wq0 + 15) >> 8) + 1;   // 1..8, wave-uniform
  f4 sc[8];
  #pragma unroll
  for (int f = 0; f < 8; f++) sc[f] = f4{0.f, 0.f, 0.f, 0.f};
  #pragma unroll
  for (int kh = 0; kh < 2; kh++) {
    const sh8 bq = kh ? bq1 : bq0;
    #pragma unroll
    for (int f = 0; f < 8; f++)
      if (f < nf) {
        sh8 ak = *(const sh8*)&SB[(f * 16 + fr) * 72 + kh * 32 + ko];
        sc[f] = __builtin_amdgcn_mfma_f32_16x16x32_bf16(ak, bq, sc[f], 0, 0, 0);
      }
  }
  float m2 = -1e30f;
  #pragma unroll
  for (int f = 0; f < 8; f++)
    #pragma unroll
    for (int r = 0; r < 4; r++) {
      const int jj = f * 16 + g * 4 + r;
      const bool ok = (jj <= 126) && (16 * jj <= i_abs);
      const float v = ok ? sc[f][r] * 0.125f : -1e30f;
      sc[f][r] = v; m2 = fmaxf(m2, v);
    }
  m2 = fmaxf(m2, __shfl_xor(m2, 16));
  m2 = fmaxf(m2, __shfl_xor(m2, 32));
  float l2 = 0.f;
  #pragma unroll
  for (int f = 0; f < 8; f++)
    #pragma unroll
    for (int r = 0; r < 4; r++) {
      const float p = __expf(sc[f][r] - m2);
      sc[f][r] = p; l2 += p;
    }
  l2 += __shfl_xor(l2, 16);
  l2 += __shfl_xor(l2, 32);
  const float inv2 = 1.f / l2;

  __syncthreads();   // barrier 2: KC region becomes P

  u16* Pw = &SB[wave * 2176];     // [16][136]
  #pragma unroll
  for (int f = 0; f < 8; f++)
    if (f < nf)
      *(ui2*)&Pw[fr * 136 + f * 16 + g * 4] =
          pk4(sc[f][0] * inv2, sc[f][1] * inv2, sc[f][2] * inv2, sc[f][3] * inv2);
  if (nf & 1)
    *(ui2*)&Pw[fr * 136 + nf * 16 + g * 4] = ui2{0u, 0u};

  f4 yacc[4];
  #pragma unroll
  for (int ni = 0; ni < 4; ni++) yacc[ni] = f4{0.f, 0.f, 0.f, 0.f};
  const int nks = (nf + 1) >> 1;
  #pragma unroll
  for (int ks = 0; ks < 4; ks++)
    if (ks < nks) {
      sh8 pa = *(const sh8*)&Pw[fr * 136 + ks * 32 + ko];
      #pragma unroll
      for (int ni = 0; ni < 4; ni++) {
        sh8 vb = *(const sh8*)&SB[9216 + (ni * 16 + fr) * 136 + ks * 32 + ko];
        yacc[ni] = __builtin_amdgcn_mfma_f32_16x16x32_bf16(pa, vb, yacc[ni], 0, 0, 0);
      }
    }

  #pragma unroll
  for (int ni = 0; ni < 4; ni++)
    #pragma unroll
    for (int r = 0; r < 4; r++)
      Pw[(4 * g + r) * 72 + ni * 16 + fr] = f2bf(yacc[ni][r]);
  u16* gy = yb2 + (size_t)(b * 2048 + wq0 + yrow) * 1024 + h * 64 + yc0;
  *(us8*)gy       = *(const us8*)&Pw[yrow * 72 + yc0];
  *(us8*)(gy + 8) = *(const us8*)&Pw[yrow * 72 + yc0 + 8];
}

// ---- yb += yb2 (bf16, elementwise, 8/thread) ----
__global__ __launch_bounds__(256)
void k_sum(u16* __restrict__ yb, const u16* __restrict__ yb2) {
  const int idx = blockIdx.x * 256 + threadIdx.x;   // < 524288
  us8 a = ((const us8*)yb)[idx];
  us8 b = ((const us8*)yb2)[idx];
  ui2 lo = pk4(bf2f(a[0]) + bf2f(b[0]), bf2f(a[1]) + bf2f(b[1]),
               bf2f(a[2]) + bf2f(b[2]), bf2f(a[3]) + bf2f(b[3]));
  ui2 hi = pk4(bf2f(a[4]) + bf2f(b[4]), bf2f(a[5]) + bf2f(b[5]),
               bf2f(a[6]) + bf2f(b[6]), bf2f(a[7]) + bf2f(b[7]));
  us8 o;
  o[0] = (u16)lo[0]; o[1] = (u16)(lo[0] >> 16); o[2] = (u16)lo[1]; o[3] = (u16)(lo[1] >> 16);
  o[4] = (u16)hi[0]; o[5] = (u16)(hi[0] >> 16); o[6] = (u16)hi[1]; o[7] = (u16)(hi[1] >> 16);
  ((us8*)yb)[idx] = o;
}

extern "C" void kernel_launch(void* const* d_in, const int* in_sizes, int n_in,
                              void* d_out, int out_size, void* d_ws, size_t ws_size,
                              hipStream_t stream) {
  const float* x  = (const float*)d_in[0];
  const float* Wq = (const float*)d_in[1];
  const float* Wl = (const float*)d_in[2];
  const float* Wc = (const float*)d_in[3];
  const float* Wo = (const float*)d_in[4];
  // dkc/dvc unused: n_def == 0 at T=2048.
  float* out = (float*)d_out;
  char* ws = (char*)d_ws;
  // workspace (~65.5 MB): vlT aliases xb (xb dead after gemm1f)
  u16* xb   = (u16*)(ws);                       //  8 MB  x bf16 [4096][1024]
  u16* vlT  = (u16*)(ws);                       //  8 MB  vl^T bf16 [32][64][2048] (after gemm1f)
  u16* Wt   = (u16*)(ws + 8388608);             // 12 MB  weights^T bf16 [6144][1024]
  u16* proj = (u16*)(ws + 20971520);            // 24 MB  [4096][3072] q|kl|vl bf16
  u16* xp   = (u16*)(ws + 46137344);            // 512 KB pooled x bf16 [256][1024]
  u16* C2   = (u16*)(ws + 46661632);            //  1 MB  pooled proj bf16 [256][2048]
  u16* kpb  = (u16*)(ws + 47710208);            // 512 KB pooled K bf16 [32][128][64]
  u16* vpT  = (u16*)(ws + 48234496);            // 512 KB pooled V^T bf16 [32][64][128]
  u16* yb   = (u16*)(ws + 48758784);            //  8 MB  y_local bf16 [4096][1024]
  u16* yb2  = (u16*)(ws + 57147392);            //  8 MB  y_comp  bf16 [4096][1024]

  k_prep<<<3840, 256, 0, stream>>>(x, Wq, Wl, Wc, Wo, xb, Wt, xp);
  k_gemm1f<<<800, 256, 0, stream>>>(xb, xp, Wt, proj, C2);
  k_poolvt<<<dim3(36, 32), 256, 0, stream>>>(proj, C2, kpb, vpT, vlT);
  k_attn<<<dim3(64, 32), 256, 0, stream>>>(proj, vlT, kpb, vpT, yb, yb2);
  k_sum<<<2048, 256, 0, stream>>>(yb, yb2);
  k_gemm2<<<dim3(16, 64), 256, 0, stream>>>(yb, Wt + (size_t)5120 * 1024, out, 4096, 1024, 1024);
}